// Round 6
// baseline (1408.205 us; speedup 1.0000x reference)
//
#include <hip/hip_runtime.h>
#include <hip/hip_bf16.h>
#include <float.h>

#define K_NEI 9
#define M 4096
#define N 65536
#define D 128
#define SEGS 16                 // 2 segments per XCD
#define SEG_LEN (N / SEGS)      // 4096 bank rows per segment
#define QB 64                   // queries per block (4 MFMA query-tiles)
#define QT 4                    // query tiles per wave
#define RT 2                    // row tiles per wave per chunk
#define BB 128                  // bank rows per chunk (32 per wave)
#define CHUNKS (SEG_LEN / BB)   // 32
#define QGROUPS (M / QB)        // 64
#define GUARD 1.0000005f

typedef __bf16 bf16x8 __attribute__((ext_vector_type(8)));
typedef float floatx4 __attribute__((ext_vector_type(4)));

static __device__ inline floatx4 mfma16(bf16x8 a, bf16x8 b, floatx4 c) {
    return __builtin_amdgcn_mfma_f32_16x16x32_bf16(a, b, c, 0, 0, 0);
}

// ---- sorted-9 toolkit -----------------------------------------------------
static __device__ inline void ce(float& a, float& b) {
    float lo = fminf(a, b), hi = fmaxf(a, b); a = lo; b = hi;
}
static __device__ inline void sort9(float t[K_NEI]) {
    ce(t[0],t[3]); ce(t[1],t[7]); ce(t[2],t[5]); ce(t[4],t[8]);
    ce(t[0],t[7]); ce(t[2],t[4]); ce(t[3],t[8]); ce(t[5],t[6]);
    ce(t[0],t[2]); ce(t[1],t[3]); ce(t[4],t[5]); ce(t[7],t[8]);
    ce(t[1],t[4]); ce(t[3],t[6]); ce(t[5],t[7]);
    ce(t[0],t[1]); ce(t[2],t[4]); ce(t[3],t[5]); ce(t[6],t[8]);
    ce(t[2],t[3]); ce(t[4],t[5]); ce(t[6],t[7]);
    ce(t[1],t[2]); ce(t[3],t[4]); ce(t[5],t[6]);
}
static __device__ inline void merge9(float t[K_NEI], const float o[K_NEI]) {
    float m[K_NEI];
#pragma unroll
    for (int i = 0; i < K_NEI; ++i) m[i] = fminf(t[i], o[K_NEI - 1 - i]);
    sort9(m);
#pragma unroll
    for (int i = 0; i < K_NEI; ++i) t[i] = m[i];
}
// pool the 4 partner lanes (lane ^16, ^32). Valid only for element-disjoint
// lists (true: each bank row is scanned by exactly one lane in pass 2).
static __device__ inline void quad_merge(float t[K_NEI]) {
    float o[K_NEI];
#pragma unroll
    for (int i = 0; i < K_NEI; ++i) o[i] = __shfl_xor(t[i], 16, 64);
    merge9(t, o);
#pragma unroll
    for (int i = 0; i < K_NEI; ++i) o[i] = __shfl_xor(t[i], 32, 64);
    merge9(t, o);
}

// ---------------------------------------------------------------------------
// Kernel 1 (prep): fp32 -> bf16 + row norms + thr_g/done init.
// Wave = 4 rows; 32 B float4x2 load per lane; 4-level 16-lane reduce;
// 16 B packed bf16 store.
// ---------------------------------------------------------------------------
static __device__ inline unsigned pack2bf(float a, float b) {
    __hip_bfloat16 x = __float2bfloat16(a), y = __float2bfloat16(b);
    unsigned short ux = *(unsigned short*)&x, uy = *(unsigned short*)&y;
    return (unsigned)ux | ((unsigned)uy << 16);
}

__global__ void prep_kernel(const float* __restrict__ bank,
                            const float* __restrict__ feats,
                            __hip_bfloat16* __restrict__ bankbf,
                            __hip_bfloat16* __restrict__ featbf,
                            float* __restrict__ bsqn,
                            float* __restrict__ qsq,
                            int* __restrict__ thr_g,
                            int* __restrict__ done) {
    int w    = (blockIdx.x * blockDim.x + threadIdx.x) >> 6;
    int lane = threadIdx.x & 63;
    int l15  = lane & 15, l4 = lane >> 4;
    int row  = w * 4 + l4;
    if (row >= N + M) return;

    const float* src = (row < N) ? (bank + (size_t)row * D)
                                 : (feats + (size_t)(row - N) * D);
    const float4* s4 = (const float4*)src;
    float4 a = s4[l15 * 2], b = s4[l15 * 2 + 1];
    float s = a.x * a.x + a.y * a.y + a.z * a.z + a.w * a.w +
              b.x * b.x + b.y * b.y + b.z * b.z + b.w * b.w;
#pragma unroll
    for (int off = 1; off < 16; off <<= 1) s += __shfl_xor(s, off, 64);

    __hip_bfloat16* dst = (row < N) ? (bankbf + (size_t)row * D)
                                    : (featbf + (size_t)(row - N) * D);
    uint4 p;
    p.x = pack2bf(a.x, a.y); p.y = pack2bf(a.z, a.w);
    p.z = pack2bf(b.x, b.y); p.w = pack2bf(b.z, b.w);
    ((uint4*)dst)[l15] = p;

    if (l15 == 0) {
        if (row < N) {
            bsqn[row] = -0.5f * s;
        } else {
            qsq[row - N] = s;
            thr_g[row - N] = 0x7f7f7f7f;   // 3.39e38f
        }
    }
    if (l15 == 1 && row >= N && (row - N) < QGROUPS) done[row - N] = 0;
}

// ---------------------------------------------------------------------------
// Kernel 2 (ROUND-6: two-pass, registers-only bounds, no key storage).
//
// Clock calibration across r0-r5 (MfmaUtil x dur vs known MFMA cycles):
// the chip runs this workload at ~714 MHz effective, consistently. So dur
// is proportional to TOTAL ISSUE CYCLES; memory latency (in cycles) is ~3x
// cheaper than at max clock and MFMA recompute is nearly free (r4: a whole
// extra GEMM cost ~0 wall time). r5's remaining cost was the key/flag
// machinery itself (64 KB LDS keys, serial bound walk, flag prefetch).
// This round deletes ALL of it:
//
// PASS 1 (full GEMM, branchless except a rarely-false ballot): per (rt,qt)
// tile compute the tile's min d2 per query (3 fmax + 1 fmaf + 2 shfl) and
// keep a per-lane sorted-9 of TILE-MINIMA in registers. 9 smallest tile-
// minima come from 9 distinct tiles => 9 distinct rows => t9[8] is a valid
// upper bound on the true 9th distance (segment rank ~9).
// Bound pooling: atomicMin to thr_g (cross-block), sm_g (cross-wave), min.
//
// PASS 2 (full GEMM + gated selection): identical MFMA scan; per tile
// 3 fmax + 1 ballot vs h = 0.5*(qs - g*GUARD); insert body only on fire
// (~10-25% of tiles with the pooled gate). Every value is tested exactly
// once with g >= true 9th at all times => per-lane t9 is exact.
//
// Epilogue: quad pool (disjoint) -> cross-wave pool via LDS -> part write;
// last seg-block per qgroup folds the 16 sorted per-seg lists.
// grid = 1024 blocks (4/CU target via launch_bounds(256,4), LDS ~10 KB),
// seg = blockIdx&7-major so each XCD keeps its 2 segments L2-resident.
// ---------------------------------------------------------------------------
__global__ __launch_bounds__(256, 4)
void knn_main(const __hip_bfloat16* __restrict__ bankbf,
              const __hip_bfloat16* __restrict__ featbf,
              const float* __restrict__ bsqn,
              const float* __restrict__ qsqp,
              int* __restrict__ thr_g,
              float* __restrict__ part,
              int* __restrict__ done,
              float* __restrict__ out) {
    __shared__ __align__(16) float sm_g[4][QB];                // 1 KB
    __shared__ __align__(16) float sm_pool[4][QB][K_NEI];      // 9 KB
    __shared__ int sm_last;

    const int tid  = threadIdx.x;
    const int lane = tid & 63;
    const int wv   = tid >> 6;
    const int l15  = lane & 15, l4 = lane >> 4;

    // seg: low 3 bits = XCD, bit 3 = which of the XCD's 2 segments
    const int seg   = (blockIdx.x & 7) | (((blockIdx.x >> 3) & 1) << 3);
    const int bq    = blockIdx.x >> 4;    // 0..63
    const int qbase = bq * QB;
    const int sbase = seg * SEG_LEN;

    // query fragments (B operand) in registers for the whole kernel
    bf16x8 qf[QT][4];
    float qs[QT];
#pragma unroll
    for (int qt = 0; qt < QT; ++qt) {
        int q = qbase + qt * 16 + l15;
        qs[qt] = qsqp[q];
#pragma unroll
        for (int ks = 0; ks < 4; ++ks)
            qf[qt][ks] = *(const bf16x8*)(featbf + (size_t)q * D + ks * 32 + l4 * 8);
    }

    // per-wave bank bases: row = sbase + wv*32 + rt*16 + l15, k-slice l4*8
    const __hip_bfloat16* ab[RT];
#pragma unroll
    for (int rt = 0; rt < RT; ++rt)
        ab[rt] = bankbf + (size_t)(sbase + wv * 32 + rt * 16 + l15) * D + l4 * 8;
    const float* ibq = bsqn + sbase + wv * 32 + l4 * 4;   // + rt*16 + ch*BB

    bf16x8 af[RT][4];
    floatx4 ini[RT];
#pragma unroll
    for (int rt = 0; rt < RT; ++rt) {
#pragma unroll
        for (int ks = 0; ks < 4; ++ks)
            af[rt][ks] = *(const bf16x8*)(ab[rt] + ks * 32);
        ini[rt] = *(const floatx4*)(ibq + rt * 16);
    }

    // t9: pass 1 = sorted-9 of tile-minima (bound); pass 2 = exact top-9
    float t9[QT][K_NEI];
#pragma unroll
    for (int qt = 0; qt < QT; ++qt)
#pragma unroll
        for (int j = 0; j < K_NEI; ++j) t9[qt][j] = FLT_MAX;

    // ================= PASS 1: full scan, tile-minima bound ================
#pragma unroll 1
    for (int ci = 0; ci < CHUNKS; ++ci) {
        floatx4 acc[RT][QT];
#pragma unroll
        for (int rt = 0; rt < RT; ++rt)
#pragma unroll
            for (int qt = 0; qt < QT; ++qt)
                acc[rt][qt] = mfma16(af[rt][0], qf[qt][0], ini[rt]);
#pragma unroll
        for (int ks = 1; ks < 4; ++ks)
#pragma unroll
            for (int rt = 0; rt < RT; ++rt)
#pragma unroll
                for (int qt = 0; qt < QT; ++qt)
                    acc[rt][qt] = mfma16(af[rt][ks], qf[qt][ks], acc[rt][qt]);

        if (ci + 1 < CHUNKS) {
            const size_t coff = (size_t)(ci + 1) * (BB * D);
#pragma unroll
            for (int rt = 0; rt < RT; ++rt) {
#pragma unroll
                for (int ks = 0; ks < 4; ++ks)
                    af[rt][ks] = *(const bf16x8*)(ab[rt] + coff + ks * 32);
                ini[rt] = *(const floatx4*)(ibq + (ci + 1) * BB + rt * 16);
            }
        }

        // tile-min per query (quad-uniform) -> sorted-9 of tile minima
#pragma unroll
        for (int rt = 0; rt < RT; ++rt) {
#pragma unroll
            for (int qt = 0; qt < QT; ++qt) {
                float m = fmaxf(fmaxf(acc[rt][qt][0], acc[rt][qt][1]),
                                fmaxf(acc[rt][qt][2], acc[rt][qt][3]));
                float k = fmaf(2.f, m, -qs[qt]);
                k = fmaxf(k, __shfl_xor(k, 16, 64));
                k = fmaxf(k, __shfl_xor(k, 32, 64));
                float d2t = fmaxf(-k, 0.f);    // min d2 of this tile, query l15
                if (__ballot(d2t < t9[qt][K_NEI - 1])) {
                    if (d2t < t9[qt][K_NEI - 1]) {
                        t9[qt][K_NEI - 1] = d2t;
#pragma unroll
                        for (int s = K_NEI - 1; s > 0; --s)
                            ce(t9[qt][s - 1], t9[qt][s]);
                    }
                }
            }
        }
    }

    // ---- pool bounds: cross-block (thr_g) + cross-wave (sm_g) -------------
    float g[QT], lastpub[QT];
#pragma unroll
    for (int qt = 0; qt < QT; ++qt) {
        float bound = t9[qt][K_NEI - 1];
        if (l4 == 0)
            atomicMin(&thr_g[qbase + qt * 16 + l15], __float_as_int(bound));
        sm_g[wv][qt * 16 + l15] = bound;
        g[qt] = bound;
    }
    __syncthreads();
#pragma unroll
    for (int qt = 0; qt < QT; ++qt) {
        float m0 = fminf(fminf(sm_g[0][qt * 16 + l15], sm_g[1][qt * 16 + l15]),
                         fminf(sm_g[2][qt * 16 + l15], sm_g[3][qt * 16 + l15]));
        g[qt] = fminf(g[qt], m0);
        int tg = __hip_atomic_load(&thr_g[qbase + qt * 16 + l15],
                                   __ATOMIC_RELAXED, __HIP_MEMORY_SCOPE_AGENT);
        g[qt] = fminf(g[qt], __int_as_float(tg));
        lastpub[qt] = g[qt];
        // reset t9 for pass 2 (per-lane exact lists, element-disjoint)
#pragma unroll
        for (int j = 0; j < K_NEI; ++j) t9[qt][j] = FLT_MAX;
    }

    // reload chunk-0 fragments for pass 2
#pragma unroll
    for (int rt = 0; rt < RT; ++rt) {
#pragma unroll
        for (int ks = 0; ks < 4; ++ks)
            af[rt][ks] = *(const bf16x8*)(ab[rt] + ks * 32);
        ini[rt] = *(const floatx4*)(ibq + rt * 16);
    }

    // ================= PASS 2: full scan, gated exact selection ============
    int tgl[QT];
#pragma unroll
    for (int qt = 0; qt < QT; ++qt) tgl[qt] = 0x7f7f7f7f;

#pragma unroll 1
    for (int ci = 0; ci < CHUNKS; ++ci) {
        float h[QT];
#pragma unroll
        for (int qt = 0; qt < QT; ++qt)
            h[qt] = 0.5f * (qs[qt] - g[qt] * GUARD);

        floatx4 acc[RT][QT];
#pragma unroll
        for (int rt = 0; rt < RT; ++rt)
#pragma unroll
            for (int qt = 0; qt < QT; ++qt)
                acc[rt][qt] = mfma16(af[rt][0], qf[qt][0], ini[rt]);
#pragma unroll
        for (int ks = 1; ks < 4; ++ks)
#pragma unroll
            for (int rt = 0; rt < RT; ++rt)
#pragma unroll
                for (int qt = 0; qt < QT; ++qt)
                    acc[rt][qt] = mfma16(af[rt][ks], qf[qt][ks], acc[rt][qt]);

        if (ci + 1 < CHUNKS) {
            const size_t coff = (size_t)(ci + 1) * (BB * D);
#pragma unroll
            for (int rt = 0; rt < RT; ++rt) {
#pragma unroll
                for (int ks = 0; ks < 4; ++ks)
                    af[rt][ks] = *(const bf16x8*)(ab[rt] + coff + ks * 32);
                ini[rt] = *(const floatx4*)(ibq + (ci + 1) * BB + rt * 16);
            }
        }

        // selection: 3 fmax + 1 ballot per tile; insert body only on fire
#pragma unroll
        for (int rt = 0; rt < RT; ++rt) {
#pragma unroll
            for (int qt = 0; qt < QT; ++qt) {
                float a0 = acc[rt][qt][0], a1 = acc[rt][qt][1];
                float a2 = acc[rt][qt][2], a3 = acc[rt][qt][3];
                float mx = fmaxf(fmaxf(a0, a1), fmaxf(a2, a3));
                if (__ballot(mx >= h[qt])) {
#pragma unroll
                    for (int r = 0; r < 4; ++r) {
                        float a = acc[rt][qt][r];
                        if (a >= h[qt]) {
                            float d2 = fmaxf(fmaf(-2.f, a, qs[qt]), 0.f);
                            if (d2 <= g[qt]) {
                                t9[qt][K_NEI - 1] = d2;
#pragma unroll
                                for (int s = K_NEI - 1; s > 0; --s)
                                    ce(t9[qt][s - 1], t9[qt][s]);
                                g[qt] = fminf(g[qt], t9[qt][K_NEI - 1]);
                            }
                        }
                    }
                }
            }
        }

        // cross-block refresh (stale = looser = safe) + throttled publish
        if ((ci & 7) == 0) {
#pragma unroll
            for (int qt = 0; qt < QT; ++qt)
                tgl[qt] = __hip_atomic_load(&thr_g[qbase + qt * 16 + l15],
                                            __ATOMIC_RELAXED,
                                            __HIP_MEMORY_SCOPE_AGENT);
        } else if ((ci & 7) == 2) {
#pragma unroll
            for (int qt = 0; qt < QT; ++qt)
                g[qt] = fminf(g[qt], __int_as_float(tgl[qt]));
        } else if ((ci & 7) == 7) {
#pragma unroll
            for (int qt = 0; qt < QT; ++qt) {
                if (g[qt] < lastpub[qt] * 0.998f) {
                    if (l4 == 0)
                        atomicMin(&thr_g[qbase + qt * 16 + l15],
                                  __float_as_int(g[qt]));
                    lastpub[qt] = g[qt];
                }
            }
        }
    }

    // ---- epilogue: quad pool (disjoint), then 4-wave pool via LDS ---------
#pragma unroll
    for (int qt = 0; qt < QT; ++qt) quad_merge(t9[qt]);
    if (l4 == 0) {
#pragma unroll
        for (int qt = 0; qt < QT; ++qt)
#pragma unroll
            for (int j = 0; j < K_NEI; ++j)
                sm_pool[wv][qt * 16 + l15][j] = t9[qt][j];
    }
    __syncthreads();
    if (tid < QB) {
        float R[K_NEI];
#pragma unroll
        for (int j = 0; j < K_NEI; ++j) R[j] = sm_pool[0][tid][j];
#pragma unroll
        for (int w = 1; w < 4; ++w) {
            float o[K_NEI];
#pragma unroll
            for (int j = 0; j < K_NEI; ++j) o[j] = sm_pool[w][tid][j];
            merge9(R, o);
        }
        float* dst = part + ((size_t)(qbase + tid) * SEGS + seg) * K_NEI;
#pragma unroll
        for (int j = 0; j < K_NEI; ++j) dst[j] = R[j];
    }

    // ---- fused final: last seg-block of this qgroup folds 16 sorted lists -
    __threadfence();
    __syncthreads();
    if (tid == 0)
        sm_last = (atomicAdd(&done[bq], 1) == SEGS - 1) ? 1 : 0;
    __syncthreads();
    if (sm_last && tid < QB) {
        int q = qbase + tid;
        const float* p = part + (size_t)q * SEGS * K_NEI;
        float R[K_NEI], nx[K_NEI];
#pragma unroll
        for (int j = 0; j < K_NEI; ++j)
            R[j] = __hip_atomic_load(p + j, __ATOMIC_RELAXED,
                                     __HIP_MEMORY_SCOPE_AGENT);
#pragma unroll
        for (int j = 0; j < K_NEI; ++j)
            nx[j] = __hip_atomic_load(p + K_NEI + j, __ATOMIC_RELAXED,
                                      __HIP_MEMORY_SCOPE_AGENT);
#pragma unroll 1
        for (int s = 1; s < SEGS; ++s) {
            float o[K_NEI];
#pragma unroll
            for (int j = 0; j < K_NEI; ++j) o[j] = nx[j];
            if (s + 1 < SEGS) {
#pragma unroll
                for (int j = 0; j < K_NEI; ++j)
                    nx[j] = __hip_atomic_load(p + (s + 1) * K_NEI + j,
                                              __ATOMIC_RELAXED,
                                              __HIP_MEMORY_SCOPE_AGENT);
            }
            merge9(R, o);
        }
        float sum = 0.f;
#pragma unroll
        for (int j = 0; j < K_NEI; ++j) sum += sqrtf(fmaxf(R[j], 0.f));
        out[q] = sum * (1.0f / 9.0f);
    }
}

// ---------------------------------------------------------------------------
extern "C" void kernel_launch(void* const* d_in, const int* in_sizes, int n_in,
                              void* d_out, int out_size, void* d_ws, size_t ws_size,
                              hipStream_t stream) {
    const float* feats = (const float*)d_in[0];   // [M, D]
    const float* bank  = (const float*)d_in[1];   // [N, D]

    char* w = (char*)d_ws;
    __hip_bfloat16* bankbf = (__hip_bfloat16*)w;                       // 16 MB
    __hip_bfloat16* featbf = (__hip_bfloat16*)(w + (size_t)N * D * 2); // 1 MB
    float* bsqn = (float*)(w + (size_t)(N + M) * D * 2);               // 256 KB
    float* qsqp = bsqn + N;                                            // 16 KB
    float* part = qsqp + M;                                            // 2.25 MB
    int*   thr_g = (int*)(part + (size_t)M * SEGS * K_NEI);            // 16 KB
    int*   done  = thr_g + M;                                          // 256 B
    float* out  = (float*)d_out;

    prep_kernel<<<(N + M) / 16, 256, 0, stream>>>(bank, feats, bankbf, featbf,
                                                  bsqn, qsqp, thr_g, done);
    knn_main<<<QGROUPS * SEGS, 256, 0, stream>>>(bankbf, featbf, bsqn, qsqp,
                                                 thr_g, part, done, out);
}

// Round 7
// 1407.091 us; speedup vs baseline: 1.0008x; 1.0008x over previous
//
#include <hip/hip_runtime.h>
#include <hip/hip_bf16.h>
#include <float.h>

#define K_NEI 9
#define M 4096
#define N 65536
#define D 128
#define SEGS 8                  // one 2 MB segment per XCD (L2-resident)
#define SEG_LEN (N / SEGS)      // 8192 bank rows per segment
#define SPLIT 2                 // blocks per segment (chunk-halves)
#define HALF_LEN (SEG_LEN / SPLIT)  // 4096 rows per block
#define LISTS (SEGS * SPLIT)    // 16 partial lists per query
#define QB 64                   // queries per block (4 MFMA query-tiles)
#define QT 4                    // query tiles per wave
#define RT 2                    // row tiles per wave per chunk
#define BB 128                  // bank rows per chunk (32 per wave)
#define CHUNKS (HALF_LEN / BB)  // 32
#define QGROUPS (M / QB)        // 64
#define GUARD 1.0000005f

typedef __bf16 bf16x8 __attribute__((ext_vector_type(8)));
typedef float floatx4 __attribute__((ext_vector_type(4)));

static __device__ inline floatx4 mfma16(bf16x8 a, bf16x8 b, floatx4 c) {
    return __builtin_amdgcn_mfma_f32_16x16x32_bf16(a, b, c, 0, 0, 0);
}

// ---- sorted-9 toolkit -----------------------------------------------------
static __device__ inline void ce(float& a, float& b) {
    float lo = fminf(a, b), hi = fmaxf(a, b); a = lo; b = hi;
}
static __device__ inline void sort9(float t[K_NEI]) {
    ce(t[0],t[3]); ce(t[1],t[7]); ce(t[2],t[5]); ce(t[4],t[8]);
    ce(t[0],t[7]); ce(t[2],t[4]); ce(t[3],t[8]); ce(t[5],t[6]);
    ce(t[0],t[2]); ce(t[1],t[3]); ce(t[4],t[5]); ce(t[7],t[8]);
    ce(t[1],t[4]); ce(t[3],t[6]); ce(t[5],t[7]);
    ce(t[0],t[1]); ce(t[2],t[4]); ce(t[3],t[5]); ce(t[6],t[8]);
    ce(t[2],t[3]); ce(t[4],t[5]); ce(t[6],t[7]);
    ce(t[1],t[2]); ce(t[3],t[4]); ce(t[5],t[6]);
}
static __device__ inline void merge9(float t[K_NEI], const float o[K_NEI]) {
    float m[K_NEI];
#pragma unroll
    for (int i = 0; i < K_NEI; ++i) m[i] = fminf(t[i], o[K_NEI - 1 - i]);
    sort9(m);
#pragma unroll
    for (int i = 0; i < K_NEI; ++i) t[i] = m[i];
}
// pool the 4 partner lanes (lane ^16, ^32). Valid only for element-disjoint
// lists (true: each bank row is scanned by exactly one lane in pass 2).
static __device__ inline void quad_merge(float t[K_NEI]) {
    float o[K_NEI];
#pragma unroll
    for (int i = 0; i < K_NEI; ++i) o[i] = __shfl_xor(t[i], 16, 64);
    merge9(t, o);
#pragma unroll
    for (int i = 0; i < K_NEI; ++i) o[i] = __shfl_xor(t[i], 32, 64);
    merge9(t, o);
}

// ---------------------------------------------------------------------------
// Kernel 1 (prep): fp32 -> bf16 + row norms + thr_g/done init.
// ---------------------------------------------------------------------------
static __device__ inline unsigned pack2bf(float a, float b) {
    __hip_bfloat16 x = __float2bfloat16(a), y = __float2bfloat16(b);
    unsigned short ux = *(unsigned short*)&x, uy = *(unsigned short*)&y;
    return (unsigned)ux | ((unsigned)uy << 16);
}

__global__ void prep_kernel(const float* __restrict__ bank,
                            const float* __restrict__ feats,
                            __hip_bfloat16* __restrict__ bankbf,
                            __hip_bfloat16* __restrict__ featbf,
                            float* __restrict__ bsqn,
                            float* __restrict__ qsq,
                            int* __restrict__ thr_g,
                            int* __restrict__ done) {
    int w    = (blockIdx.x * blockDim.x + threadIdx.x) >> 6;
    int lane = threadIdx.x & 63;
    int l15  = lane & 15, l4 = lane >> 4;
    int row  = w * 4 + l4;
    if (row >= N + M) return;

    const float* src = (row < N) ? (bank + (size_t)row * D)
                                 : (feats + (size_t)(row - N) * D);
    const float4* s4 = (const float4*)src;
    float4 a = s4[l15 * 2], b = s4[l15 * 2 + 1];
    float s = a.x * a.x + a.y * a.y + a.z * a.z + a.w * a.w +
              b.x * b.x + b.y * b.y + b.z * b.z + b.w * b.w;
#pragma unroll
    for (int off = 1; off < 16; off <<= 1) s += __shfl_xor(s, off, 64);

    __hip_bfloat16* dst = (row < N) ? (bankbf + (size_t)row * D)
                                    : (featbf + (size_t)(row - N) * D);
    uint4 p;
    p.x = pack2bf(a.x, a.y); p.y = pack2bf(a.z, a.w);
    p.z = pack2bf(b.x, b.y); p.w = pack2bf(b.z, b.w);
    ((uint4*)dst)[l15] = p;

    if (l15 == 0) {
        if (row < N) {
            bsqn[row] = -0.5f * s;
        } else {
            qsq[row - N] = s;
            thr_g[row - N] = 0x7f7f7f7f;   // 3.39e38f
        }
    }
    if (l15 == 1 && row >= N && (row - N) < QGROUPS) done[row - N] = 0;
}

// ---------------------------------------------------------------------------
// Kernel 2 (ROUND-7 = round-6 structure with L2-CORRECT geometry).
//
// r6 post-mortem: SEGS=16 put 4 MB of bank per XCD = the whole L2 ->
// thrash (FETCH 13 MB -> 3.15 GB, HBM 47% peak, 3.3x slower). Fix: back to
// SEGS=8 (one 2 MB segment per XCD, proven L2-resident r0-r5), and recover
// grid=1024 / 4 blocks/CU by splitting each segment into 2 chunk-halves:
//   seg = blockIdx&7 (== XCD), half = (blockIdx>>3)&1, bq = blockIdx>>4.
// Each block scans 4096 rows (32 chunks per pass); part = 16 lists/query.
//
// Two-pass, registers-only (r6, VGPR=64):
// PASS 1: full GEMM; per (rt,qt) tile min-d2 per query (3 fmax + fmaf +
// 2 shfl + fmax), per-lane sorted-9 of tile-minima in registers (9 distinct
// tiles => 9 distinct rows => valid 9th-distance bound). atomicMin to thr_g
// + cross-wave sm_g pool.
// PASS 2: full GEMM again (MFMA issue is ~free at 714 MHz effective clock:
// r4 showed an extra GEMM costs ~0 wall time) + ballot-gated exact
// selection with the pooled gate. Every value tested once with g >= true
// 9th => per-lane t9 exact.
// Epilogue: quad pool -> cross-wave pool -> part; last of the qgroup's 16
// blocks folds the 16 sorted lists (done counter + fence + agent loads).
// ---------------------------------------------------------------------------
__global__ __launch_bounds__(256, 4)
void knn_main(const __hip_bfloat16* __restrict__ bankbf,
              const __hip_bfloat16* __restrict__ featbf,
              const float* __restrict__ bsqn,
              const float* __restrict__ qsqp,
              int* __restrict__ thr_g,
              float* __restrict__ part,
              int* __restrict__ done,
              float* __restrict__ out) {
    __shared__ __align__(16) float sm_g[4][QB];                // 1 KB
    __shared__ __align__(16) float sm_pool[4][QB][K_NEI];      // 9 KB
    __shared__ int sm_last;

    const int tid  = threadIdx.x;
    const int lane = tid & 63;
    const int wv   = tid >> 6;
    const int l15  = lane & 15, l4 = lane >> 4;

    const int seg   = blockIdx.x & 7;          // == XCD id
    const int half  = (blockIdx.x >> 3) & 1;   // which half of the segment
    const int bq    = blockIdx.x >> 4;         // 0..63
    const int qbase = bq * QB;
    const int sbase = seg * SEG_LEN + half * HALF_LEN;
    const int list  = seg * SPLIT + half;      // 0..15

    // query fragments (B operand) in registers for the whole kernel
    bf16x8 qf[QT][4];
    float qs[QT];
#pragma unroll
    for (int qt = 0; qt < QT; ++qt) {
        int q = qbase + qt * 16 + l15;
        qs[qt] = qsqp[q];
#pragma unroll
        for (int ks = 0; ks < 4; ++ks)
            qf[qt][ks] = *(const bf16x8*)(featbf + (size_t)q * D + ks * 32 + l4 * 8);
    }

    // per-wave bank bases: row = sbase + wv*32 + rt*16 + l15, k-slice l4*8
    const __hip_bfloat16* ab[RT];
#pragma unroll
    for (int rt = 0; rt < RT; ++rt)
        ab[rt] = bankbf + (size_t)(sbase + wv * 32 + rt * 16 + l15) * D + l4 * 8;
    const float* ibq = bsqn + sbase + wv * 32 + l4 * 4;   // + rt*16 + ch*BB

    bf16x8 af[RT][4];
    floatx4 ini[RT];
#pragma unroll
    for (int rt = 0; rt < RT; ++rt) {
#pragma unroll
        for (int ks = 0; ks < 4; ++ks)
            af[rt][ks] = *(const bf16x8*)(ab[rt] + ks * 32);
        ini[rt] = *(const floatx4*)(ibq + rt * 16);
    }

    // t9: pass 1 = sorted-9 of tile-minima (bound); pass 2 = exact top-9
    float t9[QT][K_NEI];
#pragma unroll
    for (int qt = 0; qt < QT; ++qt)
#pragma unroll
        for (int j = 0; j < K_NEI; ++j) t9[qt][j] = FLT_MAX;

    // ================= PASS 1: full scan, tile-minima bound ================
#pragma unroll 1
    for (int ci = 0; ci < CHUNKS; ++ci) {
        floatx4 acc[RT][QT];
#pragma unroll
        for (int rt = 0; rt < RT; ++rt)
#pragma unroll
            for (int qt = 0; qt < QT; ++qt)
                acc[rt][qt] = mfma16(af[rt][0], qf[qt][0], ini[rt]);
#pragma unroll
        for (int ks = 1; ks < 4; ++ks)
#pragma unroll
            for (int rt = 0; rt < RT; ++rt)
#pragma unroll
                for (int qt = 0; qt < QT; ++qt)
                    acc[rt][qt] = mfma16(af[rt][ks], qf[qt][ks], acc[rt][qt]);

        if (ci + 1 < CHUNKS) {
            const size_t coff = (size_t)(ci + 1) * (BB * D);
#pragma unroll
            for (int rt = 0; rt < RT; ++rt) {
#pragma unroll
                for (int ks = 0; ks < 4; ++ks)
                    af[rt][ks] = *(const bf16x8*)(ab[rt] + coff + ks * 32);
                ini[rt] = *(const floatx4*)(ibq + (ci + 1) * BB + rt * 16);
            }
        }

        // tile-min per query (quad-uniform) -> sorted-9 of tile minima
#pragma unroll
        for (int rt = 0; rt < RT; ++rt) {
#pragma unroll
            for (int qt = 0; qt < QT; ++qt) {
                float m = fmaxf(fmaxf(acc[rt][qt][0], acc[rt][qt][1]),
                                fmaxf(acc[rt][qt][2], acc[rt][qt][3]));
                float k = fmaf(2.f, m, -qs[qt]);
                k = fmaxf(k, __shfl_xor(k, 16, 64));
                k = fmaxf(k, __shfl_xor(k, 32, 64));
                float d2t = fmaxf(-k, 0.f);    // min d2 of this tile, query l15
                if (__ballot(d2t < t9[qt][K_NEI - 1])) {
                    if (d2t < t9[qt][K_NEI - 1]) {
                        t9[qt][K_NEI - 1] = d2t;
#pragma unroll
                        for (int s = K_NEI - 1; s > 0; --s)
                            ce(t9[qt][s - 1], t9[qt][s]);
                    }
                }
            }
        }
    }

    // ---- pool bounds: cross-block (thr_g) + cross-wave (sm_g) -------------
    float g[QT], lastpub[QT];
#pragma unroll
    for (int qt = 0; qt < QT; ++qt) {
        float bound = t9[qt][K_NEI - 1];
        if (l4 == 0)
            atomicMin(&thr_g[qbase + qt * 16 + l15], __float_as_int(bound));
        sm_g[wv][qt * 16 + l15] = bound;
        g[qt] = bound;
    }
    __syncthreads();
#pragma unroll
    for (int qt = 0; qt < QT; ++qt) {
        float m0 = fminf(fminf(sm_g[0][qt * 16 + l15], sm_g[1][qt * 16 + l15]),
                         fminf(sm_g[2][qt * 16 + l15], sm_g[3][qt * 16 + l15]));
        g[qt] = fminf(g[qt], m0);
        int tg = __hip_atomic_load(&thr_g[qbase + qt * 16 + l15],
                                   __ATOMIC_RELAXED, __HIP_MEMORY_SCOPE_AGENT);
        g[qt] = fminf(g[qt], __int_as_float(tg));
        lastpub[qt] = g[qt];
        // reset t9 for pass 2 (per-lane exact lists, element-disjoint)
#pragma unroll
        for (int j = 0; j < K_NEI; ++j) t9[qt][j] = FLT_MAX;
    }

    // reload chunk-0 fragments for pass 2
#pragma unroll
    for (int rt = 0; rt < RT; ++rt) {
#pragma unroll
        for (int ks = 0; ks < 4; ++ks)
            af[rt][ks] = *(const bf16x8*)(ab[rt] + ks * 32);
        ini[rt] = *(const floatx4*)(ibq + rt * 16);
    }

    // ================= PASS 2: full scan, gated exact selection ============
    int tgl[QT];
#pragma unroll
    for (int qt = 0; qt < QT; ++qt) tgl[qt] = 0x7f7f7f7f;

#pragma unroll 1
    for (int ci = 0; ci < CHUNKS; ++ci) {
        float h[QT];
#pragma unroll
        for (int qt = 0; qt < QT; ++qt)
            h[qt] = 0.5f * (qs[qt] - g[qt] * GUARD);

        floatx4 acc[RT][QT];
#pragma unroll
        for (int rt = 0; rt < RT; ++rt)
#pragma unroll
            for (int qt = 0; qt < QT; ++qt)
                acc[rt][qt] = mfma16(af[rt][0], qf[qt][0], ini[rt]);
#pragma unroll
        for (int ks = 1; ks < 4; ++ks)
#pragma unroll
            for (int rt = 0; rt < RT; ++rt)
#pragma unroll
                for (int qt = 0; qt < QT; ++qt)
                    acc[rt][qt] = mfma16(af[rt][ks], qf[qt][ks], acc[rt][qt]);

        if (ci + 1 < CHUNKS) {
            const size_t coff = (size_t)(ci + 1) * (BB * D);
#pragma unroll
            for (int rt = 0; rt < RT; ++rt) {
#pragma unroll
                for (int ks = 0; ks < 4; ++ks)
                    af[rt][ks] = *(const bf16x8*)(ab[rt] + coff + ks * 32);
                ini[rt] = *(const floatx4*)(ibq + (ci + 1) * BB + rt * 16);
            }
        }

        // selection: 3 fmax + 1 ballot per tile; insert body only on fire
#pragma unroll
        for (int rt = 0; rt < RT; ++rt) {
#pragma unroll
            for (int qt = 0; qt < QT; ++qt) {
                float a0 = acc[rt][qt][0], a1 = acc[rt][qt][1];
                float a2 = acc[rt][qt][2], a3 = acc[rt][qt][3];
                float mx = fmaxf(fmaxf(a0, a1), fmaxf(a2, a3));
                if (__ballot(mx >= h[qt])) {
#pragma unroll
                    for (int r = 0; r < 4; ++r) {
                        float a = acc[rt][qt][r];
                        if (a >= h[qt]) {
                            float d2 = fmaxf(fmaf(-2.f, a, qs[qt]), 0.f);
                            if (d2 <= g[qt]) {
                                t9[qt][K_NEI - 1] = d2;
#pragma unroll
                                for (int s = K_NEI - 1; s > 0; --s)
                                    ce(t9[qt][s - 1], t9[qt][s]);
                                g[qt] = fminf(g[qt], t9[qt][K_NEI - 1]);
                            }
                        }
                    }
                }
            }
        }

        // cross-block refresh (stale = looser = safe) + throttled publish
        if ((ci & 7) == 0) {
#pragma unroll
            for (int qt = 0; qt < QT; ++qt)
                tgl[qt] = __hip_atomic_load(&thr_g[qbase + qt * 16 + l15],
                                            __ATOMIC_RELAXED,
                                            __HIP_MEMORY_SCOPE_AGENT);
        } else if ((ci & 7) == 2) {
#pragma unroll
            for (int qt = 0; qt < QT; ++qt)
                g[qt] = fminf(g[qt], __int_as_float(tgl[qt]));
        } else if ((ci & 7) == 7) {
#pragma unroll
            for (int qt = 0; qt < QT; ++qt) {
                if (g[qt] < lastpub[qt] * 0.998f) {
                    if (l4 == 0)
                        atomicMin(&thr_g[qbase + qt * 16 + l15],
                                  __float_as_int(g[qt]));
                    lastpub[qt] = g[qt];
                }
            }
        }
    }

    // ---- epilogue: quad pool (disjoint), then 4-wave pool via LDS ---------
#pragma unroll
    for (int qt = 0; qt < QT; ++qt) quad_merge(t9[qt]);
    if (l4 == 0) {
#pragma unroll
        for (int qt = 0; qt < QT; ++qt)
#pragma unroll
            for (int j = 0; j < K_NEI; ++j)
                sm_pool[wv][qt * 16 + l15][j] = t9[qt][j];
    }
    __syncthreads();
    if (tid < QB) {
        float R[K_NEI];
#pragma unroll
        for (int j = 0; j < K_NEI; ++j) R[j] = sm_pool[0][tid][j];
#pragma unroll
        for (int w = 1; w < 4; ++w) {
            float o[K_NEI];
#pragma unroll
            for (int j = 0; j < K_NEI; ++j) o[j] = sm_pool[w][tid][j];
            merge9(R, o);
        }
        float* dst = part + ((size_t)(qbase + tid) * LISTS + list) * K_NEI;
#pragma unroll
        for (int j = 0; j < K_NEI; ++j) dst[j] = R[j];
    }

    // ---- fused final: last block of this qgroup folds 16 sorted lists -----
    __threadfence();
    __syncthreads();
    if (tid == 0)
        sm_last = (atomicAdd(&done[bq], 1) == LISTS - 1) ? 1 : 0;
    __syncthreads();
    if (sm_last && tid < QB) {
        int q = qbase + tid;
        const float* p = part + (size_t)q * LISTS * K_NEI;
        float R[K_NEI], nx[K_NEI];
#pragma unroll
        for (int j = 0; j < K_NEI; ++j)
            R[j] = __hip_atomic_load(p + j, __ATOMIC_RELAXED,
                                     __HIP_MEMORY_SCOPE_AGENT);
#pragma unroll
        for (int j = 0; j < K_NEI; ++j)
            nx[j] = __hip_atomic_load(p + K_NEI + j, __ATOMIC_RELAXED,
                                      __HIP_MEMORY_SCOPE_AGENT);
#pragma unroll 1
        for (int s = 1; s < LISTS; ++s) {
            float o[K_NEI];
#pragma unroll
            for (int j = 0; j < K_NEI; ++j) o[j] = nx[j];
            if (s + 1 < LISTS) {
#pragma unroll
                for (int j = 0; j < K_NEI; ++j)
                    nx[j] = __hip_atomic_load(p + (s + 1) * K_NEI + j,
                                              __ATOMIC_RELAXED,
                                              __HIP_MEMORY_SCOPE_AGENT);
            }
            merge9(R, o);
        }
        float sum = 0.f;
#pragma unroll
        for (int j = 0; j < K_NEI; ++j) sum += sqrtf(fmaxf(R[j], 0.f));
        out[q] = sum * (1.0f / 9.0f);
    }
}

// ---------------------------------------------------------------------------
extern "C" void kernel_launch(void* const* d_in, const int* in_sizes, int n_in,
                              void* d_out, int out_size, void* d_ws, size_t ws_size,
                              hipStream_t stream) {
    const float* feats = (const float*)d_in[0];   // [M, D]
    const float* bank  = (const float*)d_in[1];   // [N, D]

    char* w = (char*)d_ws;
    __hip_bfloat16* bankbf = (__hip_bfloat16*)w;                       // 16 MB
    __hip_bfloat16* featbf = (__hip_bfloat16*)(w + (size_t)N * D * 2); // 1 MB
    float* bsqn = (float*)(w + (size_t)(N + M) * D * 2);               // 256 KB
    float* qsqp = bsqn + N;                                            // 16 KB
    float* part = qsqp + M;                                            // 2.25 MB
    int*   thr_g = (int*)(part + (size_t)M * LISTS * K_NEI);           // 16 KB
    int*   done  = thr_g + M;                                          // 256 B
    float* out  = (float*)d_out;

    prep_kernel<<<(N + M) / 16, 256, 0, stream>>>(bank, feats, bankbf, featbf,
                                                  bsqn, qsqp, thr_g, done);
    knn_main<<<QGROUPS * SEGS * SPLIT, 256, 0, stream>>>(bankbf, featbf, bsqn,
                                                         qsqp, thr_g, part,
                                                         done, out);
}

// Round 8
// 385.992 us; speedup vs baseline: 3.6483x; 3.6454x over previous
//
#include <hip/hip_runtime.h>
#include <hip/hip_bf16.h>
#include <float.h>

#define K_NEI 9
#define M 4096
#define N 65536
#define D 128
#define SEGS 8                  // one 2 MB segment per XCD (L2-resident)
#define SEG_LEN (N / SEGS)      // 8192 bank rows per segment
#define QB 64                   // queries per block (4 MFMA query-tiles)
#define QT 4                    // query tiles per wave
#define RT 2                    // row tiles per wave per chunk
#define BB 128                  // bank rows per chunk (32 per wave)
#define CHUNKS (SEG_LEN / BB)   // 64
#define QGROUPS (M / QB)        // 64
#define GUARD 1.0000005f

typedef __bf16 bf16x8 __attribute__((ext_vector_type(8)));
typedef float floatx4 __attribute__((ext_vector_type(4)));

static __device__ inline floatx4 mfma16(bf16x8 a, bf16x8 b, floatx4 c) {
    return __builtin_amdgcn_mfma_f32_16x16x32_bf16(a, b, c, 0, 0, 0);
}

// ---- sorted-9 toolkit -----------------------------------------------------
static __device__ inline void ce(float& a, float& b) {
    float lo = fminf(a, b), hi = fmaxf(a, b); a = lo; b = hi;
}
static __device__ inline void sort9(float t[K_NEI]) {
    ce(t[0],t[3]); ce(t[1],t[7]); ce(t[2],t[5]); ce(t[4],t[8]);
    ce(t[0],t[7]); ce(t[2],t[4]); ce(t[3],t[8]); ce(t[5],t[6]);
    ce(t[0],t[2]); ce(t[1],t[3]); ce(t[4],t[5]); ce(t[7],t[8]);
    ce(t[1],t[4]); ce(t[3],t[6]); ce(t[5],t[7]);
    ce(t[0],t[1]); ce(t[2],t[4]); ce(t[3],t[5]); ce(t[6],t[8]);
    ce(t[2],t[3]); ce(t[4],t[5]); ce(t[6],t[7]);
    ce(t[1],t[2]); ce(t[3],t[4]); ce(t[5],t[6]);
}
static __device__ inline void merge9(float t[K_NEI], const float o[K_NEI]) {
    float m[K_NEI];
#pragma unroll
    for (int i = 0; i < K_NEI; ++i) m[i] = fminf(t[i], o[K_NEI - 1 - i]);
    sort9(m);
#pragma unroll
    for (int i = 0; i < K_NEI; ++i) t[i] = m[i];
}
// pool the 4 partner lanes (lane ^16, ^32). Valid only for element-disjoint
// lists (true: each bank row is scanned by exactly one lane in pass 2).
static __device__ inline void quad_merge(float t[K_NEI]) {
    float o[K_NEI];
#pragma unroll
    for (int i = 0; i < K_NEI; ++i) o[i] = __shfl_xor(t[i], 16, 64);
    merge9(t, o);
#pragma unroll
    for (int i = 0; i < K_NEI; ++i) o[i] = __shfl_xor(t[i], 32, 64);
    merge9(t, o);
}

// ---------------------------------------------------------------------------
// Kernel 1 (prep): fp32 -> bf16 + row norms + thr_g/done init.
// ---------------------------------------------------------------------------
static __device__ inline unsigned pack2bf(float a, float b) {
    __hip_bfloat16 x = __float2bfloat16(a), y = __float2bfloat16(b);
    unsigned short ux = *(unsigned short*)&x, uy = *(unsigned short*)&y;
    return (unsigned)ux | ((unsigned)uy << 16);
}

__global__ void prep_kernel(const float* __restrict__ bank,
                            const float* __restrict__ feats,
                            __hip_bfloat16* __restrict__ bankbf,
                            __hip_bfloat16* __restrict__ featbf,
                            float* __restrict__ bsqn,
                            float* __restrict__ qsq,
                            int* __restrict__ thr_g,
                            int* __restrict__ done) {
    int w    = (blockIdx.x * blockDim.x + threadIdx.x) >> 6;
    int lane = threadIdx.x & 63;
    int l15  = lane & 15, l4 = lane >> 4;
    int row  = w * 4 + l4;
    if (row >= N + M) return;

    const float* src = (row < N) ? (bank + (size_t)row * D)
                                 : (feats + (size_t)(row - N) * D);
    const float4* s4 = (const float4*)src;
    float4 a = s4[l15 * 2], b = s4[l15 * 2 + 1];
    float s = a.x * a.x + a.y * a.y + a.z * a.z + a.w * a.w +
              b.x * b.x + b.y * b.y + b.z * b.z + b.w * b.w;
#pragma unroll
    for (int off = 1; off < 16; off <<= 1) s += __shfl_xor(s, off, 64);

    __hip_bfloat16* dst = (row < N) ? (bankbf + (size_t)row * D)
                                    : (featbf + (size_t)(row - N) * D);
    uint4 p;
    p.x = pack2bf(a.x, a.y); p.y = pack2bf(a.z, a.w);
    p.z = pack2bf(b.x, b.y); p.w = pack2bf(b.z, b.w);
    ((uint4*)dst)[l15] = p;

    if (l15 == 0) {
        if (row < N) {
            bsqn[row] = -0.5f * s;
        } else {
            qsq[row - N] = s;
            thr_g[row - N] = 0x7f7f7f7f;   // 3.39e38f
        }
    }
    if (l15 == 1 && row >= N && (row - N) < QGROUPS) done[row - N] = 0;
}

// ---------------------------------------------------------------------------
// Kernel 2 (ROUND-8 = r6's register-only two-pass at r4/r5's PROVEN memory
// geometry).
//
// Geometry evidence across rounds:  grid 1024 + 1 pass -> FETCH 15 MB
// (r2/r3); grid 512 + 2 passes -> 13 MB (r4/r5, even with 100% pass-2
// reload in r4); grid 1024 + 2 passes -> 3.2 GB L2 collapse (r6/r7, the
// pass-wraparound desyncs the per-XCD block pack). So: grid = 512, 2
// blocks/CU, SEGS=8 (seg == blockIdx&7 == XCD), each block scans its
// segment's full 8192 rows twice.
//
// PASS 1 (full GEMM): per (rt,qt) tile compute tile-min d2 per query
// (3 fmax + fmaf + 2 shfl + fmax), keep per-lane sorted-9 of TILE-MINIMA
// in registers (9 distinct tiles => 9 distinct rows => t9[8] is a valid
// upper bound on the true 9th distance; rank ~9-13 within the segment).
// Ballot-guarded insert (fires ~33x per 128 tile-events per qt).
//
// BOUND POOLING: atomicMin to thr_g (cross-block) + sm_g (cross-wave) =>
// pass-2 gate ~ global rank 30-50 => tile fire rate ~12-18%.
//
// PASS 2 (full GEMM + gated exact selection): MFMA issue is ~free (the
// workload runs at ~714 MHz effective, 8 consecutive calibrations; an
// extra GEMM pass costs ~0 wall time - r4). Per tile: 3 fmax + 1 ballot
// vs h; insert body only on fire. Every value tested once with g >= true
// 9th at all times => per-lane t9 exact.
//
// Epilogue: quad pool (disjoint) -> cross-wave pool via LDS -> part write;
// last of the qgroup's 8 blocks folds the 8 sorted lists.
// ---------------------------------------------------------------------------
__global__ __launch_bounds__(256, 2)
void knn_main(const __hip_bfloat16* __restrict__ bankbf,
              const __hip_bfloat16* __restrict__ featbf,
              const float* __restrict__ bsqn,
              const float* __restrict__ qsqp,
              int* __restrict__ thr_g,
              float* __restrict__ part,
              int* __restrict__ done,
              float* __restrict__ out) {
    __shared__ __align__(16) float sm_g[4][QB];                // 1 KB
    __shared__ __align__(16) float sm_pool[4][QB][K_NEI];      // 9 KB
    __shared__ int sm_last;

    const int tid  = threadIdx.x;
    const int lane = tid & 63;
    const int wv   = tid >> 6;
    const int l15  = lane & 15, l4 = lane >> 4;

    const int seg   = blockIdx.x & 7;          // == XCD id (L2-resident)
    const int bq    = blockIdx.x >> 3;         // 0..63
    const int qbase = bq * QB;
    const int sbase = seg * SEG_LEN;

    // query fragments (B operand) in registers for the whole kernel
    bf16x8 qf[QT][4];
    float qs[QT];
#pragma unroll
    for (int qt = 0; qt < QT; ++qt) {
        int q = qbase + qt * 16 + l15;
        qs[qt] = qsqp[q];
#pragma unroll
        for (int ks = 0; ks < 4; ++ks)
            qf[qt][ks] = *(const bf16x8*)(featbf + (size_t)q * D + ks * 32 + l4 * 8);
    }

    // per-wave bank bases: row = sbase + wv*32 + rt*16 + l15, k-slice l4*8
    const __hip_bfloat16* ab[RT];
#pragma unroll
    for (int rt = 0; rt < RT; ++rt)
        ab[rt] = bankbf + (size_t)(sbase + wv * 32 + rt * 16 + l15) * D + l4 * 8;
    const float* ibq = bsqn + sbase + wv * 32 + l4 * 4;   // + rt*16 + ch*BB

    bf16x8 af[RT][4];
    floatx4 ini[RT];
#pragma unroll
    for (int rt = 0; rt < RT; ++rt) {
#pragma unroll
        for (int ks = 0; ks < 4; ++ks)
            af[rt][ks] = *(const bf16x8*)(ab[rt] + ks * 32);
        ini[rt] = *(const floatx4*)(ibq + rt * 16);
    }

    // t9: pass 1 = sorted-9 of tile-minima (bound); pass 2 = exact top-9
    float t9[QT][K_NEI];
#pragma unroll
    for (int qt = 0; qt < QT; ++qt)
#pragma unroll
        for (int j = 0; j < K_NEI; ++j) t9[qt][j] = FLT_MAX;

    // ================= PASS 1: full scan, tile-minima bound ================
#pragma unroll 1
    for (int ci = 0; ci < CHUNKS; ++ci) {
        floatx4 acc[RT][QT];
#pragma unroll
        for (int rt = 0; rt < RT; ++rt)
#pragma unroll
            for (int qt = 0; qt < QT; ++qt)
                acc[rt][qt] = mfma16(af[rt][0], qf[qt][0], ini[rt]);
#pragma unroll
        for (int ks = 1; ks < 4; ++ks)
#pragma unroll
            for (int rt = 0; rt < RT; ++rt)
#pragma unroll
                for (int qt = 0; qt < QT; ++qt)
                    acc[rt][qt] = mfma16(af[rt][ks], qf[qt][ks], acc[rt][qt]);

        if (ci + 1 < CHUNKS) {
            const size_t coff = (size_t)(ci + 1) * (BB * D);
#pragma unroll
            for (int rt = 0; rt < RT; ++rt) {
#pragma unroll
                for (int ks = 0; ks < 4; ++ks)
                    af[rt][ks] = *(const bf16x8*)(ab[rt] + coff + ks * 32);
                ini[rt] = *(const floatx4*)(ibq + (ci + 1) * BB + rt * 16);
            }
        }

        // tile-min per query (quad-uniform) -> sorted-9 of tile minima
#pragma unroll
        for (int rt = 0; rt < RT; ++rt) {
#pragma unroll
            for (int qt = 0; qt < QT; ++qt) {
                float m = fmaxf(fmaxf(acc[rt][qt][0], acc[rt][qt][1]),
                                fmaxf(acc[rt][qt][2], acc[rt][qt][3]));
                float k = fmaf(2.f, m, -qs[qt]);
                k = fmaxf(k, __shfl_xor(k, 16, 64));
                k = fmaxf(k, __shfl_xor(k, 32, 64));
                float d2t = fmaxf(-k, 0.f);    // min d2 of this tile, query l15
                if (__ballot(d2t < t9[qt][K_NEI - 1])) {
                    if (d2t < t9[qt][K_NEI - 1]) {
                        t9[qt][K_NEI - 1] = d2t;
#pragma unroll
                        for (int s = K_NEI - 1; s > 0; --s)
                            ce(t9[qt][s - 1], t9[qt][s]);
                    }
                }
            }
        }
    }

    // ---- pool bounds: cross-block (thr_g) + cross-wave (sm_g) -------------
    float g[QT], lastpub[QT];
#pragma unroll
    for (int qt = 0; qt < QT; ++qt) {
        float bound = t9[qt][K_NEI - 1];
        if (l4 == 0)
            atomicMin(&thr_g[qbase + qt * 16 + l15], __float_as_int(bound));
        sm_g[wv][qt * 16 + l15] = bound;
        g[qt] = bound;
    }
    __syncthreads();
#pragma unroll
    for (int qt = 0; qt < QT; ++qt) {
        float m0 = fminf(fminf(sm_g[0][qt * 16 + l15], sm_g[1][qt * 16 + l15]),
                         fminf(sm_g[2][qt * 16 + l15], sm_g[3][qt * 16 + l15]));
        g[qt] = fminf(g[qt], m0);
        int tg = __hip_atomic_load(&thr_g[qbase + qt * 16 + l15],
                                   __ATOMIC_RELAXED, __HIP_MEMORY_SCOPE_AGENT);
        g[qt] = fminf(g[qt], __int_as_float(tg));
        lastpub[qt] = g[qt];
        // reset t9 for pass 2 (per-lane exact lists, element-disjoint)
#pragma unroll
        for (int j = 0; j < K_NEI; ++j) t9[qt][j] = FLT_MAX;
    }

    // reload chunk-0 fragments for pass 2
#pragma unroll
    for (int rt = 0; rt < RT; ++rt) {
#pragma unroll
        for (int ks = 0; ks < 4; ++ks)
            af[rt][ks] = *(const bf16x8*)(ab[rt] + ks * 32);
        ini[rt] = *(const floatx4*)(ibq + rt * 16);
    }

    // ================= PASS 2: full scan, gated exact selection ============
    int tgl[QT];
#pragma unroll
    for (int qt = 0; qt < QT; ++qt) tgl[qt] = 0x7f7f7f7f;

#pragma unroll 1
    for (int ci = 0; ci < CHUNKS; ++ci) {
        float h[QT];
#pragma unroll
        for (int qt = 0; qt < QT; ++qt)
            h[qt] = 0.5f * (qs[qt] - g[qt] * GUARD);

        floatx4 acc[RT][QT];
#pragma unroll
        for (int rt = 0; rt < RT; ++rt)
#pragma unroll
            for (int qt = 0; qt < QT; ++qt)
                acc[rt][qt] = mfma16(af[rt][0], qf[qt][0], ini[rt]);
#pragma unroll
        for (int ks = 1; ks < 4; ++ks)
#pragma unroll
            for (int rt = 0; rt < RT; ++rt)
#pragma unroll
                for (int qt = 0; qt < QT; ++qt)
                    acc[rt][qt] = mfma16(af[rt][ks], qf[qt][ks], acc[rt][qt]);

        if (ci + 1 < CHUNKS) {
            const size_t coff = (size_t)(ci + 1) * (BB * D);
#pragma unroll
            for (int rt = 0; rt < RT; ++rt) {
#pragma unroll
                for (int ks = 0; ks < 4; ++ks)
                    af[rt][ks] = *(const bf16x8*)(ab[rt] + coff + ks * 32);
                ini[rt] = *(const floatx4*)(ibq + (ci + 1) * BB + rt * 16);
            }
        }

        // selection: 3 fmax + 1 ballot per tile; insert body only on fire
#pragma unroll
        for (int rt = 0; rt < RT; ++rt) {
#pragma unroll
            for (int qt = 0; qt < QT; ++qt) {
                float a0 = acc[rt][qt][0], a1 = acc[rt][qt][1];
                float a2 = acc[rt][qt][2], a3 = acc[rt][qt][3];
                float mx = fmaxf(fmaxf(a0, a1), fmaxf(a2, a3));
                if (__ballot(mx >= h[qt])) {
#pragma unroll
                    for (int r = 0; r < 4; ++r) {
                        float a = acc[rt][qt][r];
                        if (a >= h[qt]) {
                            float d2 = fmaxf(fmaf(-2.f, a, qs[qt]), 0.f);
                            if (d2 <= g[qt]) {
                                t9[qt][K_NEI - 1] = d2;
#pragma unroll
                                for (int s = K_NEI - 1; s > 0; --s)
                                    ce(t9[qt][s - 1], t9[qt][s]);
                                g[qt] = fminf(g[qt], t9[qt][K_NEI - 1]);
                            }
                        }
                    }
                }
            }
        }

        // cross-block refresh (stale = looser = safe) + throttled publish
        if ((ci & 7) == 0) {
#pragma unroll
            for (int qt = 0; qt < QT; ++qt)
                tgl[qt] = __hip_atomic_load(&thr_g[qbase + qt * 16 + l15],
                                            __ATOMIC_RELAXED,
                                            __HIP_MEMORY_SCOPE_AGENT);
        } else if ((ci & 7) == 2) {
#pragma unroll
            for (int qt = 0; qt < QT; ++qt)
                g[qt] = fminf(g[qt], __int_as_float(tgl[qt]));
        } else if ((ci & 7) == 7) {
#pragma unroll
            for (int qt = 0; qt < QT; ++qt) {
                if (g[qt] < lastpub[qt] * 0.998f) {
                    if (l4 == 0)
                        atomicMin(&thr_g[qbase + qt * 16 + l15],
                                  __float_as_int(g[qt]));
                    lastpub[qt] = g[qt];
                }
            }
        }
    }

    // ---- epilogue: quad pool (disjoint), then 4-wave pool via LDS ---------
#pragma unroll
    for (int qt = 0; qt < QT; ++qt) quad_merge(t9[qt]);
    if (l4 == 0) {
#pragma unroll
        for (int qt = 0; qt < QT; ++qt)
#pragma unroll
            for (int j = 0; j < K_NEI; ++j)
                sm_pool[wv][qt * 16 + l15][j] = t9[qt][j];
    }
    __syncthreads();
    if (tid < QB) {
        float R[K_NEI];
#pragma unroll
        for (int j = 0; j < K_NEI; ++j) R[j] = sm_pool[0][tid][j];
#pragma unroll
        for (int w = 1; w < 4; ++w) {
            float o[K_NEI];
#pragma unroll
            for (int j = 0; j < K_NEI; ++j) o[j] = sm_pool[w][tid][j];
            merge9(R, o);
        }
        float* dst = part + ((size_t)(qbase + tid) * SEGS + seg) * K_NEI;
#pragma unroll
        for (int j = 0; j < K_NEI; ++j) dst[j] = R[j];
    }

    // ---- fused final: last block of this qgroup folds 8 sorted lists ------
    __threadfence();
    __syncthreads();
    if (tid == 0)
        sm_last = (atomicAdd(&done[bq], 1) == SEGS - 1) ? 1 : 0;
    __syncthreads();
    if (sm_last && tid < QB) {
        int q = qbase + tid;
        const float* p = part + (size_t)q * SEGS * K_NEI;
        float R[K_NEI], nx[K_NEI];
#pragma unroll
        for (int j = 0; j < K_NEI; ++j)
            R[j] = __hip_atomic_load(p + j, __ATOMIC_RELAXED,
                                     __HIP_MEMORY_SCOPE_AGENT);
#pragma unroll
        for (int j = 0; j < K_NEI; ++j)
            nx[j] = __hip_atomic_load(p + K_NEI + j, __ATOMIC_RELAXED,
                                      __HIP_MEMORY_SCOPE_AGENT);
#pragma unroll 1
        for (int s = 1; s < SEGS; ++s) {
            float o[K_NEI];
#pragma unroll
            for (int j = 0; j < K_NEI; ++j) o[j] = nx[j];
            if (s + 1 < SEGS) {
#pragma unroll
                for (int j = 0; j < K_NEI; ++j)
                    nx[j] = __hip_atomic_load(p + (s + 1) * K_NEI + j,
                                              __ATOMIC_RELAXED,
                                              __HIP_MEMORY_SCOPE_AGENT);
            }
            merge9(R, o);
        }
        float sum = 0.f;
#pragma unroll
        for (int j = 0; j < K_NEI; ++j) sum += sqrtf(fmaxf(R[j], 0.f));
        out[q] = sum * (1.0f / 9.0f);
    }
}

// ---------------------------------------------------------------------------
extern "C" void kernel_launch(void* const* d_in, const int* in_sizes, int n_in,
                              void* d_out, int out_size, void* d_ws, size_t ws_size,
                              hipStream_t stream) {
    const float* feats = (const float*)d_in[0];   // [M, D]
    const float* bank  = (const float*)d_in[1];   // [N, D]

    char* w = (char*)d_ws;
    __hip_bfloat16* bankbf = (__hip_bfloat16*)w;                       // 16 MB
    __hip_bfloat16* featbf = (__hip_bfloat16*)(w + (size_t)N * D * 2); // 1 MB
    float* bsqn = (float*)(w + (size_t)(N + M) * D * 2);               // 256 KB
    float* qsqp = bsqn + N;                                            // 16 KB
    float* part = qsqp + M;                                            // 1.2 MB
    int*   thr_g = (int*)(part + (size_t)M * SEGS * K_NEI);            // 16 KB
    int*   done  = thr_g + M;                                          // 256 B
    float* out  = (float*)d_out;

    prep_kernel<<<(N + M) / 16, 256, 0, stream>>>(bank, feats, bankbf, featbf,
                                                  bsqn, qsqp, thr_g, done);
    knn_main<<<QGROUPS * SEGS, 256, 0, stream>>>(bankbf, featbf, bsqn, qsqp,
                                                 thr_g, part, done, out);
}